// Round 3
// baseline (112.613 us; speedup 1.0000x reference)
//
#include <hip/hip_runtime.h>
#include <math.h>

#define PROJ 8192
#define NB   16
#define NC   512
#define HW   196    // 14*14
#define NKC  7      // K chunks of 32 (196 zero-padded to 224)
#define LST  40     // LDS row stride in bf16 elems (80 B: b128-aligned, 2-way banks = free)
#define MAGIC 0x13579BDFu   // flag sentinel: bytes all distinct -> byte-fill poison can't forge it

typedef __attribute__((ext_vector_type(8))) short bf16x8;   // MFMA A/B frag
typedef __attribute__((ext_vector_type(4))) short short4v;
typedef __attribute__((ext_vector_type(4))) float f32x4;    // MFMA C/D frag

__device__ __forceinline__ unsigned bf16_rne(float f) {
    unsigned u = __builtin_bit_cast(unsigned, f);
    return (u + 0x7fffu + ((u >> 16) & 1u)) >> 16;
}

// ---------------------------------------------------------------------------
// Fused kernel, plain launch, NO spin-waits (deadlock-proof at any residency).
// grid = 256 blocks x 512 threads.
//
// Phase 1 (identical to verified cbp_gram_mfma): split-bf16 MFMA 128x128 Gram
// tile + scatter into private LDS sketch -> dense dump to ws.
//   block -> (batch,tile): b = 2*(blk&7) + (blk>>7), tile = (blk>>3)&15
//   (inverse: physical block for (b,t) = ((b&1)<<7) | (t<<3) | (b>>1);
//    all 16 blocks of a batch share blk%8 -> same XCD -> L2-local partials)
//
// Tail ("last block finalizes", no waiting):
//   - seq_cst store MAGIC flag; single seq_cst read of the batch's 16 flags.
//   - not all set -> EXIT (no spin).  The last storer is guaranteed to see
//     all 16 (seq_cst total order); duplicates are idempotent (identical
//     inputs -> identical outputs).
//   - finalizer: per bin sum 16 partials, signed sqrt, in-block ssq reduce,
//     L2-normalize, single y write.
// ---------------------------------------------------------------------------
__global__ __launch_bounds__(512, 2)
void cbp_fused(const float* __restrict__ x,
               const float* __restrict__ s1,
               const float* __restrict__ s2,
               const int*   __restrict__ h1,
               const int*   __restrict__ h2,
               float* __restrict__ ws,
               float* __restrict__ y) {
    __shared__ float sk[PROJ];         // 32 KB private sketch (reused in finalize)
    __shared__ short Ah[128 * LST];    // 10 KB each
    __shared__ short Al[128 * LST];
    __shared__ short Bh[128 * LST];
    __shared__ short Bl[128 * LST];
    __shared__ int   lh1[128], lh2[128];
    __shared__ float lsA[128], lsB[128];
    __shared__ int   ndone;

    const int tid = threadIdx.x;
    const int blk = blockIdx.x;
    const int b    = 2 * (blk & 7) + (blk >> 7);   // XCD-pinned batch
    const int tile = (blk >> 3) & 15;
    const int I = tile >> 2, J = tile & 3;
    const int c1base = I * 128;
    const int c2base = J * 128;

    const int lane = tid & 63;
    const int wave = tid >> 6;         // 0..7
    const int quad = lane >> 4;
    const int l15  = lane & 15;
    const int wr   = (wave >> 1) * 32; // wave's 32x64 sub-tile
    const int wc   = (wave & 1) * 64;

    unsigned* flags = (unsigned*)(ws + (size_t)256 * PROJ);   // 256 words

    for (int i = tid; i < PROJ; i += 512) sk[i] = 0.f;
    if (tid < 128) {
        lh1[tid] = h1[c1base + tid];  lsA[tid] = s1[c1base + tid];
        lh2[tid] = h2[c2base + tid];  lsB[tid] = s2[c2base + tid];
    }

    const float* xa = x + ((size_t)b * NC + c1base) * HW;
    const float* xb = x + ((size_t)b * NC + c2base) * HW;

    f32x4 acc[2][4];
#pragma unroll
    for (int i = 0; i < 2; ++i)
#pragma unroll
        for (int j = 0; j < 4; ++j) acc[i][j] = (f32x4){0.f, 0.f, 0.f, 0.f};

    // Staging assignment: thread handles rows sr0 and sr0+64, float4 slot sq.
    const int sr0 = tid >> 3;          // 0..63
    const int sq  = tid & 7;           // 0..7

    float4 pa[2], pb[2];
    {   // prologue: load chunk 0
        const int kk = 4 * sq;
        const bool ok = (kk + 3 < HW);
#pragma unroll
        for (int h = 0; h < 2; ++h) {
            const int r = sr0 + 64 * h;
            pa[h] = ok ? *(const float4*)&xa[r * HW + kk] : (float4){0.f,0.f,0.f,0.f};
            pb[h] = ok ? *(const float4*)&xb[r * HW + kk] : (float4){0.f,0.f,0.f,0.f};
        }
    }

    for (int kc = 0; kc < NKC; ++kc) {
        __syncthreads();               // LDS free; also covers lh/ls on kc==0
        // Convert + store current chunk (signs folded; exact for +-1).
#pragma unroll
        for (int h = 0; h < 2; ++h) {
            const int r = sr0 + 64 * h;
            const float sA = lsA[r], sB = lsB[r];
            const float fa[4] = {pa[h].x*sA, pa[h].y*sA, pa[h].z*sA, pa[h].w*sA};
            const float fb[4] = {pb[h].x*sB, pb[h].y*sB, pb[h].z*sB, pb[h].w*sB};
            short4v ah, al, bh, bl;
#pragma unroll
            for (int c = 0; c < 4; ++c) {
                const unsigned ha_ = bf16_rne(fa[c]);
                ah[c] = (short)ha_;
                al[c] = (short)bf16_rne(fa[c] - __builtin_bit_cast(float, ha_ << 16));
                const unsigned hb_ = bf16_rne(fb[c]);
                bh[c] = (short)hb_;
                bl[c] = (short)bf16_rne(fb[c] - __builtin_bit_cast(float, hb_ << 16));
            }
            *(short4v*)&Ah[r * LST + 4 * sq] = ah;
            *(short4v*)&Al[r * LST + 4 * sq] = al;
            *(short4v*)&Bh[r * LST + 4 * sq] = bh;
            *(short4v*)&Bl[r * LST + 4 * sq] = bl;
        }
        // Prefetch next chunk while this chunk computes.
        if (kc + 1 < NKC) {
            const int kk = (kc + 1) * 32 + 4 * sq;
            const bool ok = (kk + 3 < HW);
#pragma unroll
            for (int h = 0; h < 2; ++h) {
                const int r = sr0 + 64 * h;
                pa[h] = ok ? *(const float4*)&xa[r * HW + kk] : (float4){0.f,0.f,0.f,0.f};
                pb[h] = ok ? *(const float4*)&xb[r * HW + kk] : (float4){0.f,0.f,0.f,0.f};
            }
        }
        __syncthreads();

        bf16x8 ahf[2], alf[2], bhf[4], blf[4];
#pragma unroll
        for (int i = 0; i < 2; ++i) {
            const int ra = wr + i * 16 + l15;
            ahf[i] = *(const bf16x8*)&Ah[ra * LST + quad * 8];
            alf[i] = *(const bf16x8*)&Al[ra * LST + quad * 8];
        }
#pragma unroll
        for (int j = 0; j < 4; ++j) {
            const int rb = wc + j * 16 + l15;
            bhf[j] = *(const bf16x8*)&Bh[rb * LST + quad * 8];
            blf[j] = *(const bf16x8*)&Bl[rb * LST + quad * 8];
        }
#pragma unroll
        for (int i = 0; i < 2; ++i)
#pragma unroll
            for (int j = 0; j < 4; ++j) {
                acc[i][j] = __builtin_amdgcn_mfma_f32_16x16x32_bf16(ahf[i], bhf[j], acc[i][j], 0, 0, 0);
                acc[i][j] = __builtin_amdgcn_mfma_f32_16x16x32_bf16(ahf[i], blf[j], acc[i][j], 0, 0, 0);
                acc[i][j] = __builtin_amdgcn_mfma_f32_16x16x32_bf16(alf[i], bhf[j], acc[i][j], 0, 0, 0);
            }
    }
    __syncthreads();

    // Scatter (signs pre-folded): C/D layout col=lane&15, row=quad*4+reg.
#pragma unroll
    for (int i = 0; i < 2; ++i) {
        const int lr0 = wr + i * 16 + quad * 4;
#pragma unroll
        for (int j = 0; j < 4; ++j) {
            const int h2v = lh2[wc + j * 16 + l15];
#pragma unroll
            for (int rg = 0; rg < 4; ++rg) {
                const int bin = (lh1[lr0 + rg] + h2v) & (PROJ - 1);
                atomicAdd(&sk[bin], acc[i][j][rg]);   // ds_add_f32
            }
        }
    }
    __syncthreads();

    {   // dump private sketch to ws
        float4* dst = (float4*)(ws + (size_t)blk * PROJ);
        const float4* src = (const float4*)sk;
        for (int i = tid; i < PROJ / 4; i += 512) dst[i] = src[i];
    }
    __syncthreads();   // barrier drains vmcnt(0): dump globally visible (L2)

    // ---- arrival flag (no waiting anywhere below) ----
    if (tid == 0) {
        ndone = 0;
        __hip_atomic_store(&flags[blk], MAGIC, __ATOMIC_SEQ_CST,
                           __HIP_MEMORY_SCOPE_AGENT);
    }
    __syncthreads();   // own store complete before peer reads

    if (tid < 16) {
        const int pblk = ((b & 1) << 7) | (tid << 3) | (b >> 1);
        const unsigned f = __hip_atomic_load(&flags[pblk], __ATOMIC_SEQ_CST,
                                             __HIP_MEMORY_SCOPE_AGENT);
        if (f == MAGIC) atomicAdd(&ndone, 1);
    }
    __syncthreads();
    if (ndone < 16) return;            // not the last arrival -> exit, no spin

    // ---- finalize batch b (last block; duplicates are idempotent) ----
    float ov[16];
    float myssq = 0.f;
#pragma unroll
    for (int i = 0; i < 16; ++i) {
        const int bin = tid + 512 * i;
        float s = 0.f;
#pragma unroll
        for (int t = 0; t < 16; ++t) {
            const int pblk = ((b & 1) << 7) | (t << 3) | (b >> 1);
            s += ws[(size_t)pblk * PROJ + bin];
        }
        const float m = sqrtf(fabsf(s) + 1e-8f);
        const float o = (s > 0.f) ? m : (s < 0.f ? -m : 0.f);   // sign(0)=0
        ov[i] = o;
        myssq += o * o;
    }

    sk[tid] = myssq;                   // sk reused as 512-wide reduction scratch
    __syncthreads();
#pragma unroll
    for (int st = 256; st >= 1; st >>= 1) {
        if (tid < st) sk[tid] += sk[tid + st];
        __syncthreads();
    }
    const float inv = 1.0f / fmaxf(sqrtf(sk[0]), 1e-12f);

#pragma unroll
    for (int i = 0; i < 16; ++i)
        y[(size_t)b * PROJ + tid + 512 * i] = ov[i] * inv;
}

// ---------------------------------------------------------------------------
extern "C" void kernel_launch(void* const* d_in, const int* in_sizes, int n_in,
                              void* d_out, int out_size, void* d_ws, size_t ws_size,
                              hipStream_t stream) {
    const float* x  = (const float*)d_in[0];
    const float* s1 = (const float*)d_in[1];
    const float* s2 = (const float*)d_in[2];
    const int*   h1 = (const int*)d_in[3];
    const int*   h2 = (const int*)d_in[4];
    float* y  = (float*)d_out;                     // [16, 8192]
    float* ws = (float*)d_ws;                      // 256 partial sketches + flags

    hipLaunchKernelGGL(cbp_fused, dim3(256), dim3(512), 0, stream,
                       x, s1, s2, h1, h2, ws, y);
}

// Round 5
// 106.710 us; speedup vs baseline: 1.0553x; 1.0553x over previous
//
#include <hip/hip_runtime.h>
#include <math.h>

#define PROJ 8192
#define NB   16
#define NC   512
#define HW   196    // 14*14
#define NKC  7      // K chunks of 32 (196 zero-padded to 224)

typedef __attribute__((ext_vector_type(8))) short bf16x8;   // MFMA A/B frag
typedef __attribute__((ext_vector_type(4))) float f32x4;    // MFMA C/D frag

__device__ __forceinline__ unsigned bf16_rne(float f) {
    unsigned u = __builtin_bit_cast(unsigned, f);
    return (u + 0x7fffu + ((u >> 16) & 1u)) >> 16;
}

// Split one sign-weighted 8-float group into hi/lo bf16 fragments.
// Integer-RNE path — identical arithmetic to the verified 103.8us baseline.
__device__ __forceinline__ void cvt_frag(const float4 f0, const float4 f1,
                                         const float s, bf16x8& hi, bf16x8& lo) {
    const float f[8] = {f0.x * s, f0.y * s, f0.z * s, f0.w * s,
                        f1.x * s, f1.y * s, f1.z * s, f1.w * s};
    bf16x8 h, l;
#pragma unroll
    for (int c = 0; c < 8; ++c) {
        const unsigned hu = bf16_rne(f[c]);
        h[c] = (short)hu;
        l[c] = (short)bf16_rne(f[c] - __builtin_bit_cast(float, hu << 16));
    }
    hi = h;
    lo = l;
}

// ---------------------------------------------------------------------------
// Kernel 1: barrier-free Gram. grid = 256 x 512 (8 waves). No LDS staging of
// X: each wave loads MFMA fragments straight from global (x is L2-resident;
// rows are 784 B = 16B-aligned, k-offsets 32B-aligned -> aligned float4).
// Redundancy (A x2, B x4 across waves) ~172 MB from L2 ~ 5 us -- far cheaper
// than the 15-barrier lockstep this replaces (measured 90% stall).
// K-loop: explicit 2-deep double buffer, fully unrolled (static indices).
// Only 2 barriers total (before scatter, before dump).
//   block -> (batch,tile): b = 2*(blk&7) + (blk>>7), tile = (blk>>3)&15
// ---------------------------------------------------------------------------
__global__ __launch_bounds__(512, 2)
void cbp_gram(const float* __restrict__ x,
              const float* __restrict__ s1,
              const float* __restrict__ s2,
              const int*   __restrict__ h1,
              const int*   __restrict__ h2,
              float* __restrict__ ws) {
    __shared__ float sk[PROJ];         // 32 KB private sketch
    __shared__ int   lh1[128], lh2[128];

    const int tid = threadIdx.x;
    const int blk = blockIdx.x;
    const int b    = 2 * (blk & 7) + (blk >> 7);   // XCD-pinned batch
    const int tile = (blk >> 3) & 15;
    const int c1base = (tile >> 2) * 128;
    const int c2base = (tile & 3) * 128;

    const int lane = tid & 63;
    const int wave = tid >> 6;         // 0..7
    const int quad = lane >> 4;        // k-slot: k = kc*32 + quad*8 .. +7
    const int l15  = lane & 15;
    const int wr   = (wave >> 1) * 32; // wave's 32x64 sub-tile
    const int wc   = (wave & 1) * 64;

    for (int i = tid; i < PROJ; i += 512) sk[i] = 0.f;
    if (tid < 128) { lh1[tid] = h1[c1base + tid]; lh2[tid] = h2[c2base + tid]; }

    const float* xa = x + ((size_t)b * NC + c1base) * HW;
    const float* xb = x + ((size_t)b * NC + c2base) * HW;

    // Per-lane fragment row pointers + signs (hoisted out of K-loop).
    const float* pA[2]; float sa[2];
#pragma unroll
    for (int i = 0; i < 2; ++i) {
        const int r = wr + i * 16 + l15;
        pA[i] = xa + r * HW;
        sa[i] = s1[c1base + r];
    }
    const float* pB[4]; float sb[4];
#pragma unroll
    for (int j = 0; j < 4; ++j) {
        const int r = wc + j * 16 + l15;
        pB[j] = xb + r * HW;
        sb[j] = s2[c2base + r];
    }

    f32x4 acc[2][4];
#pragma unroll
    for (int i = 0; i < 2; ++i)
#pragma unroll
        for (int j = 0; j < 4; ++j) acc[i][j] = (f32x4){0.f, 0.f, 0.f, 0.f};

    const float4 z4 = {0.f, 0.f, 0.f, 0.f};
    float4 buf[2][12];                 // [parity][A0,A0',A1,A1',B0,B0',..,B3']
                                       // all indices compile-time (full unroll)

    // Load chunk kc's 6 fragments (2 float4 each) into buf[par]. Tail chunk
    // (kc==6) masks k>=196 to zero; predicated loads never deref OOB lanes.
#define LOADC(par, kc) do {                                                   \
    const int kk_ = (kc) * 32 + quad * 8;                                     \
    const bool ok0_ = (kk_ + 3) < HW, ok1_ = (kk_ + 7) < HW;                  \
    _Pragma("unroll") for (int i_ = 0; i_ < 2; ++i_) {                        \
        buf[par][2*i_]   = ok0_ ? *(const float4*)(pA[i_] + kk_)     : z4;    \
        buf[par][2*i_+1] = ok1_ ? *(const float4*)(pA[i_] + kk_ + 4) : z4; }  \
    _Pragma("unroll") for (int j_ = 0; j_ < 4; ++j_) {                        \
        buf[par][4+2*j_]   = ok0_ ? *(const float4*)(pB[j_] + kk_)     : z4;  \
        buf[par][4+2*j_+1] = ok1_ ? *(const float4*)(pB[j_] + kk_ + 4) : z4; }\
} while (0)

    LOADC(0, 0);
#pragma unroll
    for (int kc = 0; kc < NKC; ++kc) {
        const int cur = kc & 1;
        if (kc + 1 < NKC) LOADC(cur ^ 1, kc + 1);   // prefetch next chunk

        bf16x8 ah[2], al[2], bh[4], bl[4];
#pragma unroll
        for (int i = 0; i < 2; ++i)
            cvt_frag(buf[cur][2*i], buf[cur][2*i+1], sa[i], ah[i], al[i]);
#pragma unroll
        for (int j = 0; j < 4; ++j)
            cvt_frag(buf[cur][4+2*j], buf[cur][4+2*j+1], sb[j], bh[j], bl[j]);

#pragma unroll
        for (int i = 0; i < 2; ++i)
#pragma unroll
            for (int j = 0; j < 4; ++j) {
                acc[i][j] = __builtin_amdgcn_mfma_f32_16x16x32_bf16(ah[i], bh[j], acc[i][j], 0, 0, 0);
                acc[i][j] = __builtin_amdgcn_mfma_f32_16x16x32_bf16(ah[i], bl[j], acc[i][j], 0, 0, 0);
                acc[i][j] = __builtin_amdgcn_mfma_f32_16x16x32_bf16(al[i], bh[j], acc[i][j], 0, 0, 0);
            }
    }
#undef LOADC

    __syncthreads();   // sk zeroed + lh1/lh2 ready (first barrier in kernel)

    // Scatter (signs pre-folded): C/D layout col=lane&15, row=quad*4+reg.
#pragma unroll
    for (int i = 0; i < 2; ++i) {
        const int lr0 = wr + i * 16 + quad * 4;
#pragma unroll
        for (int j = 0; j < 4; ++j) {
            const int h2v = lh2[wc + j * 16 + l15];
#pragma unroll
            for (int rg = 0; rg < 4; ++rg) {
                const int bin = (lh1[lr0 + rg] + h2v) & (PROJ - 1);
                atomicAdd(&sk[bin], acc[i][j][rg]);   // ds_add_f32
            }
        }
    }
    __syncthreads();

    // Dump private sketch to ws.
    float4* dst = (float4*)(ws + (size_t)blk * PROJ);
    const float4* src = (const float4*)sk;
    for (int i = tid; i < PROJ / 4; i += 512) dst[i] = src[i];
}

__device__ __forceinline__ float ssqrt(float s) {
    const float m = sqrtf(fabsf(s) + 1e-8f);
    return (s > 0.f) ? m : (s < 0.f ? -m : 0.f);   // sign(0)=0
}

// ---------------------------------------------------------------------------
// Kernel 2: per-batch finalize. grid = 16 x 512. Sum 16 partials/bin (same
// t-order as verified reduce), signed sqrt, ssq shuffle-reduce, normalize,
// single y write (no y roundtrip).
// ---------------------------------------------------------------------------
__global__ __launch_bounds__(512)
void cbp_finalize(const float* __restrict__ ws, float* __restrict__ y) {
    __shared__ float red[8];
    const int b   = blockIdx.x;
    const int tid = threadIdx.x;
    const int pbase = ((b & 1) << 7) | (b >> 1);   // physical partial base

    float4 ov[4];
    float ssq = 0.f;
#pragma unroll
    for (int g = 0; g < 4; ++g) {
        const int f4 = tid + 512 * g;              // float4 index in [0,2048)
        float4 s = {0.f, 0.f, 0.f, 0.f};
#pragma unroll
        for (int t = 0; t < 16; ++t) {
            const float4 v =
                ((const float4*)(ws + (size_t)(pbase | (t << 3)) * PROJ))[f4];
            s.x += v.x; s.y += v.y; s.z += v.z; s.w += v.w;
        }
        float4 o;
        o.x = ssqrt(s.x); o.y = ssqrt(s.y); o.z = ssqrt(s.z); o.w = ssqrt(s.w);
        ov[g] = o;
        ssq += o.x * o.x + o.y * o.y + o.z * o.z + o.w * o.w;
    }

    float v = ssq;
#pragma unroll
    for (int off = 32; off >= 1; off >>= 1) v += __shfl_xor(v, off, 64);
    if ((tid & 63) == 0) red[tid >> 6] = v;
    __syncthreads();
    float tot = 0.f;
#pragma unroll
    for (int w = 0; w < 8; ++w) tot += red[w];
    const float inv = 1.0f / fmaxf(sqrtf(tot), 1e-12f);

    float4* yp = (float4*)(y + (size_t)b * PROJ);
#pragma unroll
    for (int g = 0; g < 4; ++g) {
        float4 o = ov[g];
        o.x *= inv; o.y *= inv; o.z *= inv; o.w *= inv;
        yp[tid + 512 * g] = o;
    }
}

// ---------------------------------------------------------------------------
extern "C" void kernel_launch(void* const* d_in, const int* in_sizes, int n_in,
                              void* d_out, int out_size, void* d_ws, size_t ws_size,
                              hipStream_t stream) {
    const float* x  = (const float*)d_in[0];
    const float* s1 = (const float*)d_in[1];
    const float* s2 = (const float*)d_in[2];
    const int*   h1 = (const int*)d_in[3];
    const int*   h2 = (const int*)d_in[4];
    float* y  = (float*)d_out;                     // [16, 8192]
    float* ws = (float*)d_ws;                      // 256 partial sketches (8 MB)

    hipLaunchKernelGGL(cbp_gram, dim3(256), dim3(512), 0, stream,
                       x, s1, s2, h1, h2, ws);
    hipLaunchKernelGGL(cbp_finalize, dim3(16), dim3(512), 0, stream, ws, y);
}